// Round 19
// baseline (355.343 us; speedup 1.0000x reference)
//
#include <hip/hip_runtime.h>
#include <math.h>

typedef _Float16 f16;
typedef _Float16 half8 __attribute__((ext_vector_type(8)));
typedef _Float16 half4v __attribute__((ext_vector_type(4)));
typedef _Float16 half2v __attribute__((ext_vector_type(2)));
typedef float floatx4 __attribute__((ext_vector_type(4)));
typedef unsigned int u32;

#define AS1 __attribute__((address_space(1)))
#define AS3 __attribute__((address_space(3)))

// async global->LDS, 16B per lane; LDS dest is wave-uniform base + lane*16.
__device__ __forceinline__ void stage16(f16* l, const f16* g) {
    __builtin_amdgcn_global_load_lds((const AS1 u32*)g, (AS3 u32*)l, 16, 0, 0);
}

// ---------------- fused prep: cvt(hidden) + pack(qkv_w) + pack(proj_w) ----------------
__device__ __forceinline__ void pack_body(const float* __restrict__ Wf,
                                          f16* __restrict__ Wp, int p) {
    const int lane = p & 63;
    const int j = (p >> 6) & 3;
    const int sk = p >> 8;            // slab*40 + k0
    const int k0 = sk % 40;
    const int slab = sk / 40;
    const int row = slab * 64 + j * 16 + (lane & 15);
    const int col = k0 * 32 + (lane >> 4) * 8;
    const float* src = Wf + (size_t)row * 1280 + col;
    float4 a = *(const float4*)src;
    float4 b = *(const float4*)(src + 4);
    half8 h = {(f16)a.x, (f16)a.y, (f16)a.z, (f16)a.w,
               (f16)b.x, (f16)b.y, (f16)b.z, (f16)b.w};
    *(half8*)(Wp + (size_t)p * 8) = h;
}

__global__ __launch_bounds__(256) void prep_kernel(const float* __restrict__ hidden,
                                                   f16* __restrict__ A16,
                                                   const float* __restrict__ qkv_w,
                                                   f16* __restrict__ WP16,
                                                   const float* __restrict__ proj_w,
                                                   f16* __restrict__ PP16) {
    const int b = blockIdx.x;
    if (b < 10240) {
        const int i = b * 256 + threadIdx.x;        // < 2,621,440 exactly
        float4 v = ((const float4*)hidden)[i];
        half4v h = {(f16)v.x, (f16)v.y, (f16)v.z, (f16)v.w};
        ((half4v*)A16)[i] = h;
    } else if (b < 12640) {
        pack_body(qkv_w, WP16, (b - 10240) * 256 + threadIdx.x);
    } else {
        pack_body(proj_w, PP16, (b - 12640) * 256 + threadIdx.x);
    }
}

// ---------------- QKV GEMM: 3-buffer A, corrected vmcnt retirement ----------------
// R19: R18's tail bug fixed -- stage guard was `i < 8`, skipping A(19); kt=19
// then computed on stale A(16) (absmax 0.308). Now `i < 9` (stage all
// k0+3 <= 19), matching the verified ledger:
//  steady even: queue [A(k0)4 B(k0)8 A(k0+1)4 B(k0+1)8 A(k0+2)4]=28,
//   vmcnt(16) retires exactly A(k0),B(k0); A-distance ~3 phases, B ~1.5.
//  i=8 odd: 28 -> retires A17,B17. i=9 even: 24 -> vmcnt(12) retires A18,B18.
//  i=9 odd: vmcnt(0) drains A19,B19. Buffer = kt%3; WAR guarded by alpha.
constexpr int GK = 1280;
constexpr int KT = 20;   // 1280 / 64

template <int MT>
__global__ __launch_bounds__(512, 2) void gemm_bp(const f16* __restrict__ A,
                                                  const f16* __restrict__ Bp,
                                                  const float* __restrict__ bias,
                                                  f16* __restrict__ outH,
                                                  float* __restrict__ outF,
                                                  int N, int NT) {
    constexpr int M_FR = MT / 32;        // per-wave m-fragments
    constexpr int QE = MT * 32;          // f16 per k-slice quarter
    __shared__ f16 sm[3][2][QE];         // [buf][ks][quarter]  96 KiB
    const int t = threadIdx.x;
    const int lane = t & 63, w = t >> 6;
    const int wm = w >> 2, wn = w & 3;   // 2M x 4N waves
    const int c16 = lane & 15, quad = lane >> 4;
    const int id = blockIdx.x;
    const int nx = (int)gridDim.x >> 3;
    const int gid = (id & 7) * nx + (id >> 3);
    const int bm = gid / NT, bn = gid - bm * NT;
    const f16* Ab = A + (size_t)bm * MT * GK;
    const f16* Bw = Bp + (size_t)(bn * 4 + wn) * (40 * 4 * 64 * 8) + lane * 8;

    floatx4 acc[M_FR][4] = {};
    half8 bfA[8], bfB[8];

    auto stageA = [&](int kt, int dst) {
#pragma unroll
        for (int ks = 0; ks < 2; ks++)
#pragma unroll
            for (int u = 0; u < MT / 128; u++) {
                const int c = t + u * 512;
                const int row = c >> 2;
                const int lc = ((c & 3) - (row >> 1)) & 3;  // inverse swizzle on src
                stage16(&sm[dst][ks][0] + c * 8,
                        Ab + (size_t)row * GK + kt * 64 + ks * 32 + lc * 8);
            }
    };
    auto loadB = [&](int kt, half8(&bf)[8]) {
#pragma unroll
        for (int ks = 0; ks < 2; ks++)
#pragma unroll
            for (int j = 0; j < 4; j++)
                bf[ks * 4 + j] = *(const half8*)(Bw + (size_t)((kt * 2 + ks) * 4 + j) * 512);
    };
    auto compute = [&](int b, half8(&bf)[8]) {
#pragma unroll
        for (int ks = 0; ks < 2; ks++) {
            const f16* q = &sm[b][ks][0];
#pragma unroll
            for (int m = 0; m < M_FR; m++) {
                const int r = wm * (MT / 2) + m * 16 + c16;
                half8 a = *(const half8*)(q + r * 32 + (((quad + (r >> 1)) & 3) * 8));
#pragma unroll
                for (int n = 0; n < 4; n++)
                    acc[m][n] = __builtin_amdgcn_mfma_f32_16x16x32_f16(a, bf[ks * 4 + n],
                                                                       acc[m][n], 0, 0, 0);
            }
        }
    };

    // Prologue: A(0), B(0), A(1) -> 16 outstanding.
    stageA(0, 0);
    loadB(0, bfA);
    stageA(1, 1);

    for (int i = 0; i < 10; i++) {
        const int k0 = 2 * i;
        const int be = k0 % 3, bo = (k0 + 1) % 3;
        const int b2 = (k0 + 2) % 3, b3 = (k0 + 3) % 3;
        // ---- even half: consume buf[be] + bfA(=B(k0)) ----
        asm volatile("s_waitcnt lgkmcnt(0)" ::: "memory");
        __builtin_amdgcn_s_barrier();                  // alpha: buf[b2] readers done
        loadB(k0 + 1, bfB);                            // k0+1 <= 19 always
        if (i < 9) {
            stageA(k0 + 2, b2);
            asm volatile("s_waitcnt vmcnt(16)" ::: "memory");  // retire A(k0),B(k0) exactly
        } else {
            asm volatile("s_waitcnt vmcnt(12)" ::: "memory");  // tail: leave A(19),B(19)
        }
        __builtin_amdgcn_s_barrier();                  // beta: buf[be] + bfA valid
        compute(be, bfA);
        // ---- odd half: consume buf[bo] + bfB(=B(k0+1)) ----
        asm volatile("s_waitcnt lgkmcnt(0)" ::: "memory");
        __builtin_amdgcn_s_barrier();                  // alpha: buf[b3] readers done
        if (i < 9) {
            loadB(k0 + 2, bfA);
            stageA(k0 + 3, b3);                        // k0+3 <= 19 for i <= 8
            asm volatile("s_waitcnt vmcnt(16)" ::: "memory");  // retire A(k0+1),B(k0+1)
        } else {
            asm volatile("s_waitcnt vmcnt(0)" ::: "memory");   // drain A(19),B(19)
        }
        __builtin_amdgcn_s_barrier();                  // beta: buf[bo] + bfB valid
        compute(bo, bfB);
    }

    const int colBase = bn * 256 + wn * 64;
    const size_t rowBase = (size_t)bm * MT + wm * (MT / 2);
    float bv[4];
#pragma unroll
    for (int n = 0; n < 4; n++) bv[n] = bias[colBase + n * 16 + c16];
#pragma unroll
    for (int m = 0; m < M_FR; m++) {
#pragma unroll
        for (int r = 0; r < 4; r++) {
            const size_t row = rowBase + m * 16 + quad * 4 + r;
#pragma unroll
            for (int n = 0; n < 4; n++) {
                const int col = colBase + n * 16 + c16;
                const float v = acc[m][n][r] + bv[n];
                if (outH) outH[row * (size_t)N + col] = (f16)v;
                else      outF[row * (size_t)N + col] = v;
            }
        }
    }
}

// ---------------- proj GEMM: XCD-grouped 1D grid ----------------
__global__ __launch_bounds__(256) void gemm_nt(const f16* __restrict__ A,
                                               const f16* __restrict__ Bp,
                                               const float* __restrict__ bias,
                                               f16* __restrict__ outH,
                                               float* __restrict__ outF, int N, int NB) {
    __shared__ f16 As[128 * 32];
    const int t = threadIdx.x;
    const int lane = t & 63;
    const int w = t >> 6;
    const int wm = w & 1, wn = w >> 1;
    const int c16 = lane & 15, quad = lane >> 4;
    const int id = blockIdx.x;
    const int xcd = id & 7;
    const int m = id >> 3;
    const size_t bm = xcd + 8 * (m / NB);
    const size_t bn = m % NB;
    const f16* Ab = A + bm * 128 * GK;
    const f16* Bw = Bp + (size_t)(bn * 2 + wn) * (40 * 4 * 64 * 8);
    floatx4 acc[4][4] = {};
    const int c0 = t, c1 = t + 256;
    const int r0 = c0 >> 2, kc0 = ((c0 & 3) - (r0 >> 1)) & 3;
    const int r1 = c1 >> 2, kc1 = ((c1 & 3) - (r1 >> 1)) & 3;
    for (int k0i = 0; k0i < 40; k0i++) {
        const int k0 = k0i * 32;
        stage16(As + c0 * 8, Ab + (size_t)r0 * GK + k0 + kc0 * 8);
        stage16(As + c1 * 8, Ab + (size_t)r1 * GK + k0 + kc1 * 8);
        half8 bf[4];
#pragma unroll
        for (int j = 0; j < 4; j++)
            bf[j] = *(const half8*)(Bw + (((size_t)k0i * 4 + j) * 64 + lane) * 8);
        __syncthreads();
        half8 af[4];
#pragma unroll
        for (int i = 0; i < 4; i++) {
            const int row = wm * 64 + i * 16 + c16;
            af[i] = *(const half8*)(As + (4 * row + ((quad + (row >> 1)) & 3)) * 8);
        }
#pragma unroll
        for (int i = 0; i < 4; i++)
#pragma unroll
            for (int j = 0; j < 4; j++)
                acc[i][j] = __builtin_amdgcn_mfma_f32_16x16x32_f16(af[i], bf[j], acc[i][j], 0, 0, 0);
        __syncthreads();
    }
#pragma unroll
    for (int i = 0; i < 4; i++) {
#pragma unroll
        for (int j = 0; j < 4; j++) {
            const int col = (int)bn * 128 + wn * 64 + j * 16 + c16;
            const float bv = bias[col];
#pragma unroll
            for (int r = 0; r < 4; r++) {
                const size_t row = bm * 128 + wm * 64 + i * 16 + quad * 4 + r;
                const float v = acc[i][j][r] + bv;
                if (outH) outH[row * (size_t)N + col] = (f16)v;
                else      outF[row * (size_t)N + col] = v;
            }
        }
    }
}

// ---------------- RoPE + layout: qkv[S,3840] -> QB/KB [H][S][96], VT [H*80][S] ----------------
#define QSCALE (0.11180339887498949f * 1.4426950408889634f)

__global__ __launch_bounds__(320) void rope_kernel(const f16* __restrict__ qkv,
                                                   const float* __restrict__ cosp,
                                                   const float* __restrict__ sinp,
                                                   f16* __restrict__ qb, f16* __restrict__ kb,
                                                   f16* __restrict__ vt) {
    constexpr int S = 8192;
    const int bs = blockIdx.x, h = blockIdx.y, t = threadIdx.x;
    const int sl = t / 5, g = t % 5;   // 64 s-rows x 5 groups of 8 d-pairs
    const int s = bs * 64 + sl;
    {
        const size_t base = (size_t)s * 3840 + h * 80 + g * 8;
        half8 qa = *(const half8*)(qkv + base);
        half8 qc = *(const half8*)(qkv + base + 40);
        half8 ka = *(const half8*)(qkv + base + 1280);
        half8 kc = *(const half8*)(qkv + base + 1320);
        const float* cp = cosp + (size_t)s * 80 + g * 8;
        const float* sp = sinp + (size_t)s * 80 + g * 8;
        half8 qo0, qo1, ko0, ko1;
#pragma unroll
        for (int j = 0; j < 8; j++) {
            float c0 = cp[j], c1 = cp[j + 40];
            float n0 = sp[j], n1 = sp[j + 40];
            float q0 = (float)qa[j], q1 = (float)qc[j];
            float k0 = (float)ka[j], k1 = (float)kc[j];
            qo0[j] = (f16)((q0 * c0 - q1 * n0) * QSCALE);
            qo1[j] = (f16)((q1 * c1 + q0 * n1) * QSCALE);
            ko0[j] = (f16)(k0 * c0 - k1 * n0);
            ko1[j] = (f16)(k1 * c1 + k0 * n1);
        }
        const size_t ob = ((size_t)h * S + s) * 96 + g * 8;
        *(half8*)(qb + ob)      = qo0;
        *(half8*)(qb + ob + 40) = qo1;
        *(half8*)(kb + ob)      = ko0;
        *(half8*)(kb + ob + 40) = ko1;
        if (g < 2) {  // pads 80..95
            half8 qp = {}, kp = {};
            if (g == 0) { qp[0] = (f16)(-8.0f); kp[0] = (f16)(1.0f); }
            const size_t pb = ((size_t)h * S + s) * 96 + 80 + g * 8;
            *(half8*)(qb + pb) = qp;
            *(half8*)(kb + pb) = kp;
        }
    }
    // v transpose via LDS: [64 s][80 d] -> VT[h*80+d][s]
    __shared__ f16 vls[64][81];
    for (int j = t; j < 640; j += 320) {           // input: 640 half8 units, 2/thread
        const int s2 = j / 10, gg = j - s2 * 10;
        half8 v = *(const half8*)(qkv + ((size_t)(bs * 64 + s2)) * 3840 + 2560 + h * 80 + gg * 8);
#pragma unroll
        for (int i = 0; i < 8; i++) vls[s2][gg * 8 + i] = v[i];
    }
    __syncthreads();
    for (int j = t; j < 640; j += 320) {           // output: 640 half8 units, 2/thread
        const int d = j >> 3, sb = j & 7;
        half8 v;
#pragma unroll
        for (int i = 0; i < 8; i++) v[i] = vls[sb * 8 + i][d];
        *(half8*)(vt + ((size_t)(h * 80 + d)) * S + bs * 64 + sb * 8) = v;
    }
}

// ---------------- flash attention: R0 structure exactly (measured best 71.2us) ----------------
__global__ __launch_bounds__(256, 2) void attn_kernel(const f16* __restrict__ qb,
                                                      const f16* __restrict__ kb,
                                                      const f16* __restrict__ vt,
                                                      const int* __restrict__ cu,
                                                      f16* __restrict__ out) {
    constexpr int S = 8192;
    __shared__ f16 Ks[2][64 * 96];   // 24576 B (double-buffered, swizzled)
    __shared__ f16 Ps[256 * 72];     // 36864 B (wave-private 64-q slabs)
    const int t = threadIdx.x, lane = t & 63, w = t >> 6;
    const int c16 = lane & 15, quad = lane >> 4;
    const int id = blockIdx.x;
    const int pair = id & 127;
    const int qt = id >> 7;          // 0..3: which 256-row q tile
    const int h = pair & 15, z = pair >> 4;
    const int s0 = cu[z];

    half8 qf[4][3];
#pragma unroll
    for (int qt2 = 0; qt2 < 4; qt2++)
#pragma unroll
        for (int ks = 0; ks < 3; ks++)
            qf[qt2][ks] = *(const half8*)(qb + ((size_t)h * S + s0 + qt * 256 + w * 64 + qt2 * 16 + c16) * 96 + ks * 32 + quad * 8);

    const f16 ov = (c16 == 0) ? (f16)1.f : (f16)0.f;
    const half8 onesf = {ov, ov, ov, ov, ov, ov, ov, ov};

    const int sR = t >> 2;
    const int sK = ((t & 3) - (sR >> 1)) & 3;

    {   // stage K tile 0
        const f16* Kg = kb + ((size_t)h * S + s0) * 96;
#pragma unroll
        for (int j = 0; j < 3; j++)
            stage16(&Ks[0][0] + (j * 256 + t) * 8, Kg + (size_t)sR * 96 + j * 32 + sK * 8);
    }
    __syncthreads();

    floatx4 o[6][4] = {};   // O^T tiles [d-tile][q-subtile]; dt=5 row 80 = l

    for (int kv = 0; kv < 16; kv++) {
        if (kv < 15) {  // stage next K tile into the other buffer
            const f16* Kg = kb + ((size_t)h * S + s0 + (kv + 1) * 64) * 96;
            f16* Kd = &Ks[(kv + 1) & 1][0];
#pragma unroll
            for (int j = 0; j < 3; j++)
                stage16(Kd + (j * 256 + t) * 8, Kg + (size_t)sR * 96 + j * 32 + sK * 8);
        }
        const f16* Kc = &Ks[kv & 1][0];
        floatx4 sc[4][4] = {};
#pragma unroll
        for (int ks = 0; ks < 3; ks++) {
            half8 kf[4];
#pragma unroll
            for (int mt = 0; mt < 4; mt++) {
                const int row = mt * 16 + c16;
                kf[mt] = *(const half8*)(Kc + (ks * 256 + 4 * row + ((quad + (row >> 1)) & 3)) * 8);
            }
#pragma unroll
            for (int qt2 = 0; qt2 < 4; qt2++)
#pragma unroll
                for (int mt = 0; mt < 4; mt++)
                    sc[mt][qt2] = __builtin_amdgcn_mfma_f32_16x16x32_f16(kf[mt], qf[qt2][ks], sc[mt][qt2], 0, 0, 0);
        }
#pragma unroll
        for (int qt2 = 0; qt2 < 4; qt2++) {
            const int q = w * 64 + qt2 * 16 + c16;
#pragma unroll
            for (int mt = 0; mt < 4; mt++) {
                half4v pv;
#pragma unroll
                for (int r = 0; r < 4; r++)
                    pv[r] = (f16)__builtin_amdgcn_exp2f(sc[mt][qt2][r]);
                *(half4v*)(Ps + q * 72 + mt * 16 + quad * 4) = pv;
            }
        }
#pragma unroll
        for (int ks = 0; ks < 2; ks++) {
            const f16* Vg = vt + (size_t)h * 80 * S + s0 + kv * 64 + ks * 32;
            half8 vf[5];
#pragma unroll
            for (int dt = 0; dt < 5; dt++)
                vf[dt] = *(const half8*)(Vg + (size_t)(dt * 16 + c16) * S + quad * 8);
#pragma unroll
            for (int qt2 = 0; qt2 < 4; qt2++) {
                const int q = w * 64 + qt2 * 16 + c16;
                half8 pf = *(const half8*)(Ps + q * 72 + ks * 32 + quad * 8);
#pragma unroll
                for (int dt = 0; dt < 5; dt++)
                    o[dt][qt2] = __builtin_amdgcn_mfma_f32_16x16x32_f16(vf[dt], pf, o[dt][qt2], 0, 0, 0);
                o[5][qt2] = __builtin_amdgcn_mfma_f32_16x16x32_f16(onesf, pf, o[5][qt2], 0, 0, 0);
            }
        }
        __syncthreads();
    }
#pragma unroll
    for (int qt2 = 0; qt2 < 4; qt2++) {
        const float l = __shfl(o[5][qt2][0], c16);
        const float inv = 1.f / l;
        const size_t srow = (size_t)s0 + qt * 256 + w * 64 + qt2 * 16 + c16;
#pragma unroll
        for (int dt = 0; dt < 5; dt++)
#pragma unroll
            for (int rp = 0; rp < 2; rp++) {
                half2v hv = {(f16)(o[dt][qt2][rp * 2] * inv), (f16)(o[dt][qt2][rp * 2 + 1] * inv)};
                *(half2v*)(out + srow * 1280 + h * 80 + dt * 16 + quad * 4 + rp * 2) = hv;
            }
    }
}

// ---------------- launch: 5 dispatches ----------------
extern "C" void kernel_launch(void* const* d_in, const int* in_sizes, int n_in,
                              void* d_out, int out_size, void* d_ws, size_t ws_size,
                              hipStream_t stream) {
    const float* hidden = (const float*)d_in[0];
    const int* cu       = (const int*)d_in[1];
    const float* cosp   = (const float*)d_in[2];
    const float* sinp   = (const float*)d_in[3];
    const float* qkv_w  = (const float*)d_in[4];
    const float* qkv_b  = (const float*)d_in[5];
    const float* proj_w = (const float*)d_in[6];
    const float* proj_b = (const float*)d_in[7];
    float* out = (float*)d_out;

    constexpr size_t S = 8192, DIM = 1280, N3 = 3840;
    f16* A16   = (f16*)d_ws;
    f16* WP16  = A16 + S * DIM;          // packed qkv_w
    f16* PP16  = WP16 + N3 * DIM;        // packed proj_w
    f16* QKV16 = PP16 + DIM * DIM;
    f16* QB    = QKV16 + S * N3;
    f16* KB    = QB + (size_t)16 * S * 96;
    f16* VT    = KB + (size_t)16 * S * 96;
    f16* AT16  = A16;  // reuse: hidden-f16 dead after QKV GEMM

    prep_kernel<<<13440, 256, 0, stream>>>(hidden, A16, qkv_w, WP16, proj_w, PP16);
    gemm_bp<256><<<32 * 15, 512, 0, stream>>>(A16, WP16, qkv_b, QKV16, nullptr, 3840, 15);
    rope_kernel<<<dim3(128, 16), 320, 0, stream>>>(QKV16, cosp, sinp, QB, KB, VT);
    attn_kernel<<<512, 256, 0, stream>>>(QB, KB, VT, cu, A16);
    gemm_nt<<<640, 256, 0, stream>>>(AT16, PP16, proj_b, nullptr, out, 1280, 10);
}

// Round 20
// 353.018 us; speedup vs baseline: 1.0066x; 1.0066x over previous
//
#include <hip/hip_runtime.h>
#include <math.h>

typedef _Float16 f16;
typedef _Float16 half8 __attribute__((ext_vector_type(8)));
typedef _Float16 half4v __attribute__((ext_vector_type(4)));
typedef _Float16 half2v __attribute__((ext_vector_type(2)));
typedef float floatx4 __attribute__((ext_vector_type(4)));
typedef unsigned int u32;

#define AS1 __attribute__((address_space(1)))
#define AS3 __attribute__((address_space(3)))

// async global->LDS, 16B per lane; LDS dest is wave-uniform base + lane*16.
__device__ __forceinline__ void stage16(f16* l, const f16* g) {
    __builtin_amdgcn_global_load_lds((const AS1 u32*)g, (AS3 u32*)l, 16, 0, 0);
}

// ---------------- fused prep: cvt(hidden) + pack(qkv_w) + pack(proj_w) ----------------
__device__ __forceinline__ void pack_body(const float* __restrict__ Wf,
                                          f16* __restrict__ Wp, int p) {
    const int lane = p & 63;
    const int j = (p >> 6) & 3;
    const int sk = p >> 8;            // slab*40 + k0
    const int k0 = sk % 40;
    const int slab = sk / 40;
    const int row = slab * 64 + j * 16 + (lane & 15);
    const int col = k0 * 32 + (lane >> 4) * 8;
    const float* src = Wf + (size_t)row * 1280 + col;
    float4 a = *(const float4*)src;
    float4 b = *(const float4*)(src + 4);
    half8 h = {(f16)a.x, (f16)a.y, (f16)a.z, (f16)a.w,
               (f16)b.x, (f16)b.y, (f16)b.z, (f16)b.w};
    *(half8*)(Wp + (size_t)p * 8) = h;
}

__global__ __launch_bounds__(256) void prep_kernel(const float* __restrict__ hidden,
                                                   f16* __restrict__ A16,
                                                   const float* __restrict__ qkv_w,
                                                   f16* __restrict__ WP16,
                                                   const float* __restrict__ proj_w,
                                                   f16* __restrict__ PP16) {
    const int b = blockIdx.x;
    if (b < 10240) {
        const int i = b * 256 + threadIdx.x;        // < 2,621,440 exactly
        float4 v = ((const float4*)hidden)[i];
        half4v h = {(f16)v.x, (f16)v.y, (f16)v.z, (f16)v.w};
        ((half4v*)A16)[i] = h;
    } else if (b < 12640) {
        pack_body(qkv_w, WP16, (b - 10240) * 256 + threadIdx.x);
    } else {
        pack_body(proj_w, PP16, (b - 12640) * 256 + threadIdx.x);
    }
}

// ---------------- QKV GEMM (final: measured best 107.5-110us, 2-buffer) ----------------
// CLOSED after SEVEN falsified theories: time invariant to schedule structure
// (5 variants), occupancy (1 vs 2 blocks/CU), HBM traffic (90/163/277 MB),
// and prefetch depth (R19: corrected 3-buffer/3-phase-ahead vmcnt ledger ==
// identical 30% MfmaUtil). The wall is the m233-class lockstep 2-phase stall;
// only a faithful fine-interleaved 8-phase role-split breaks it (R1's naive
// port regressed). This is the session's practical plateau for this GEMM.
constexpr int GK = 1280;
constexpr int KT = 20;   // 1280 / 64

template <int MT>
__global__ __launch_bounds__(512, 2) void gemm_bp(const f16* __restrict__ A,
                                                  const f16* __restrict__ Bp,
                                                  const float* __restrict__ bias,
                                                  f16* __restrict__ outH,
                                                  float* __restrict__ outF,
                                                  int N, int NT) {
    constexpr int M_FR = MT / 32;        // per-wave m-fragments
    constexpr int QE = MT * 32;          // f16 per quarter
    __shared__ f16 sm[2][2][QE];         // [buf][ks][quarter]
    const int t = threadIdx.x;
    const int lane = t & 63, w = t >> 6;
    const int wm = w >> 2, wn = w & 3;   // 2M x 4N waves
    const int c16 = lane & 15, quad = lane >> 4;
    const int id = blockIdx.x;
    const int nx = (int)gridDim.x >> 3;
    const int gid = (id & 7) * nx + (id >> 3);
    const int bm = gid / NT, bn = gid - bm * NT;
    const f16* Ab = A + (size_t)bm * MT * GK;
    const f16* Bw = Bp + (size_t)(bn * 4 + wn) * (40 * 4 * 64 * 8) + lane * 8;

    floatx4 acc[M_FR][4] = {};
    half8 bfA[8], bfB[8];

    auto stageA = [&](int kt, int dst) {
#pragma unroll
        for (int ks = 0; ks < 2; ks++)
#pragma unroll
            for (int u = 0; u < MT / 128; u++) {
                const int c = t + u * 512;
                const int row = c >> 2;
                const int lc = ((c & 3) - (row >> 1)) & 3;  // inverse swizzle on src
                stage16(&sm[dst][ks][0] + c * 8,
                        Ab + (size_t)row * GK + kt * 64 + ks * 32 + lc * 8);
            }
    };
    auto loadB = [&](int kt, half8(&bf)[8]) {
#pragma unroll
        for (int ks = 0; ks < 2; ks++)
#pragma unroll
            for (int j = 0; j < 4; j++)
                bf[ks * 4 + j] = *(const half8*)(Bw + (size_t)((kt * 2 + ks) * 4 + j) * 512);
    };
    auto compute = [&](int p, half8(&bf)[8]) {
#pragma unroll
        for (int ks = 0; ks < 2; ks++) {
            const f16* q = &sm[p][ks][0];
#pragma unroll
            for (int m = 0; m < M_FR; m++) {
                const int r = wm * (MT / 2) + m * 16 + c16;
                half8 a = *(const half8*)(q + r * 32 + (((quad + (r >> 1)) & 3) * 8));
#pragma unroll
                for (int n = 0; n < 4; n++)
                    acc[m][n] = __builtin_amdgcn_mfma_f32_16x16x32_f16(a, bf[ks * 4 + n],
                                                                       acc[m][n], 0, 0, 0);
            }
        }
    };
#define WAIT_STEADY()                                              \
    if constexpr (MT == 256) {                                     \
        asm volatile("s_waitcnt vmcnt(12)" ::: "memory");          \
    } else {                                                       \
        asm volatile("s_waitcnt vmcnt(10)" ::: "memory");          \
    }

    stageA(0, 0);
    loadB(0, bfA);
    asm volatile("s_waitcnt vmcnt(8)" ::: "memory");
    __builtin_amdgcn_s_barrier();

    for (int i = 0; i < 10; i++) {
        const int k0 = 2 * i;
        asm volatile("s_waitcnt lgkmcnt(0)" ::: "memory");
        __builtin_amdgcn_s_barrier();                  // alpha: buf1 free
        stageA(k0 + 1, 1);
        loadB(k0 + 1, bfB);
        WAIT_STEADY();
        __builtin_amdgcn_s_barrier();                  // beta: buf0 valid
        compute(0, bfA);
        asm volatile("s_waitcnt lgkmcnt(0)" ::: "memory");
        __builtin_amdgcn_s_barrier();                  // alpha: buf0 free
        if (i < 9) {
            stageA(k0 + 2, 0);
            loadB(k0 + 2, bfA);
            WAIT_STEADY();
        } else {
            asm volatile("s_waitcnt vmcnt(0)" ::: "memory");
        }
        __builtin_amdgcn_s_barrier();                  // beta: buf1 valid
        compute(1, bfB);
    }

    const int colBase = bn * 256 + wn * 64;
    const size_t rowBase = (size_t)bm * MT + wm * (MT / 2);
    float bv[4];
#pragma unroll
    for (int n = 0; n < 4; n++) bv[n] = bias[colBase + n * 16 + c16];
#pragma unroll
    for (int m = 0; m < M_FR; m++) {
#pragma unroll
        for (int r = 0; r < 4; r++) {
            const size_t row = rowBase + m * 16 + quad * 4 + r;
#pragma unroll
            for (int n = 0; n < 4; n++) {
                const int col = colBase + n * 16 + c16;
                const float v = acc[m][n][r] + bv[n];
                if (outH) outH[row * (size_t)N + col] = (f16)v;
                else      outF[row * (size_t)N + col] = v;
            }
        }
    }
}

// ---------------- proj GEMM: XCD-grouped 1D grid ----------------
__global__ __launch_bounds__(256) void gemm_nt(const f16* __restrict__ A,
                                               const f16* __restrict__ Bp,
                                               const float* __restrict__ bias,
                                               f16* __restrict__ outH,
                                               float* __restrict__ outF, int N, int NB) {
    __shared__ f16 As[128 * 32];
    const int t = threadIdx.x;
    const int lane = t & 63;
    const int w = t >> 6;
    const int wm = w & 1, wn = w >> 1;
    const int c16 = lane & 15, quad = lane >> 4;
    const int id = blockIdx.x;
    const int xcd = id & 7;
    const int m = id >> 3;
    const size_t bm = xcd + 8 * (m / NB);
    const size_t bn = m % NB;
    const f16* Ab = A + bm * 128 * GK;
    const f16* Bw = Bp + (size_t)(bn * 2 + wn) * (40 * 4 * 64 * 8);
    floatx4 acc[4][4] = {};
    const int c0 = t, c1 = t + 256;
    const int r0 = c0 >> 2, kc0 = ((c0 & 3) - (r0 >> 1)) & 3;
    const int r1 = c1 >> 2, kc1 = ((c1 & 3) - (r1 >> 1)) & 3;
    for (int k0i = 0; k0i < 40; k0i++) {
        const int k0 = k0i * 32;
        stage16(As + c0 * 8, Ab + (size_t)r0 * GK + k0 + kc0 * 8);
        stage16(As + c1 * 8, Ab + (size_t)r1 * GK + k0 + kc1 * 8);
        half8 bf[4];
#pragma unroll
        for (int j = 0; j < 4; j++)
            bf[j] = *(const half8*)(Bw + (((size_t)k0i * 4 + j) * 64 + lane) * 8);
        __syncthreads();
        half8 af[4];
#pragma unroll
        for (int i = 0; i < 4; i++) {
            const int row = wm * 64 + i * 16 + c16;
            af[i] = *(const half8*)(As + (4 * row + ((quad + (row >> 1)) & 3)) * 8);
        }
#pragma unroll
        for (int i = 0; i < 4; i++)
#pragma unroll
            for (int j = 0; j < 4; j++)
                acc[i][j] = __builtin_amdgcn_mfma_f32_16x16x32_f16(af[i], bf[j], acc[i][j], 0, 0, 0);
        __syncthreads();
    }
#pragma unroll
    for (int i = 0; i < 4; i++) {
#pragma unroll
        for (int j = 0; j < 4; j++) {
            const int col = (int)bn * 128 + wn * 64 + j * 16 + c16;
            const float bv = bias[col];
#pragma unroll
            for (int r = 0; r < 4; r++) {
                const size_t row = bm * 128 + wm * 64 + i * 16 + quad * 4 + r;
                const float v = acc[i][j][r] + bv;
                if (outH) outH[row * (size_t)N + col] = (f16)v;
                else      outF[row * (size_t)N + col] = v;
            }
        }
    }
}

// ---------------- RoPE + layout: qkv[S,3840] -> QB/KB [H][S][96], VT [H*80][S] ----------------
#define QSCALE (0.11180339887498949f * 1.4426950408889634f)

__global__ __launch_bounds__(320) void rope_kernel(const f16* __restrict__ qkv,
                                                   const float* __restrict__ cosp,
                                                   const float* __restrict__ sinp,
                                                   f16* __restrict__ qb, f16* __restrict__ kb,
                                                   f16* __restrict__ vt) {
    constexpr int S = 8192;
    const int bs = blockIdx.x, h = blockIdx.y, t = threadIdx.x;
    const int sl = t / 5, g = t % 5;   // 64 s-rows x 5 groups of 8 d-pairs
    const int s = bs * 64 + sl;
    {
        const size_t base = (size_t)s * 3840 + h * 80 + g * 8;
        half8 qa = *(const half8*)(qkv + base);
        half8 qc = *(const half8*)(qkv + base + 40);
        half8 ka = *(const half8*)(qkv + base + 1280);
        half8 kc = *(const half8*)(qkv + base + 1320);
        const float* cp = cosp + (size_t)s * 80 + g * 8;
        const float* sp = sinp + (size_t)s * 80 + g * 8;
        half8 qo0, qo1, ko0, ko1;
#pragma unroll
        for (int j = 0; j < 8; j++) {
            float c0 = cp[j], c1 = cp[j + 40];
            float n0 = sp[j], n1 = sp[j + 40];
            float q0 = (float)qa[j], q1 = (float)qc[j];
            float k0 = (float)ka[j], k1 = (float)kc[j];
            qo0[j] = (f16)((q0 * c0 - q1 * n0) * QSCALE);
            qo1[j] = (f16)((q1 * c1 + q0 * n1) * QSCALE);
            ko0[j] = (f16)(k0 * c0 - k1 * n0);
            ko1[j] = (f16)(k1 * c1 + k0 * n1);
        }
        const size_t ob = ((size_t)h * S + s) * 96 + g * 8;
        *(half8*)(qb + ob)      = qo0;
        *(half8*)(qb + ob + 40) = qo1;
        *(half8*)(kb + ob)      = ko0;
        *(half8*)(kb + ob + 40) = ko1;
        if (g < 2) {  // pads 80..95
            half8 qp = {}, kp = {};
            if (g == 0) { qp[0] = (f16)(-8.0f); kp[0] = (f16)(1.0f); }
            const size_t pb = ((size_t)h * S + s) * 96 + 80 + g * 8;
            *(half8*)(qb + pb) = qp;
            *(half8*)(kb + pb) = kp;
        }
    }
    // v transpose via LDS: [64 s][80 d] -> VT[h*80+d][s]
    __shared__ f16 vls[64][81];
    for (int j = t; j < 640; j += 320) {           // input: 640 half8 units, 2/thread
        const int s2 = j / 10, gg = j - s2 * 10;
        half8 v = *(const half8*)(qkv + ((size_t)(bs * 64 + s2)) * 3840 + 2560 + h * 80 + gg * 8);
#pragma unroll
        for (int i = 0; i < 8; i++) vls[s2][gg * 8 + i] = v[i];
    }
    __syncthreads();
    for (int j = t; j < 640; j += 320) {           // output: 640 half8 units, 2/thread
        const int d = j >> 3, sb = j & 7;
        half8 v;
#pragma unroll
        for (int i = 0; i < 8; i++) v[i] = vls[sb * 8 + i][d];
        *(half8*)(vt + ((size_t)(h * 80 + d)) * S + bs * 64 + sb * 8) = v;
    }
}

// ---------------- flash attention: R0 structure exactly (measured best 71.2us) ----------------
__global__ __launch_bounds__(256, 2) void attn_kernel(const f16* __restrict__ qb,
                                                      const f16* __restrict__ kb,
                                                      const f16* __restrict__ vt,
                                                      const int* __restrict__ cu,
                                                      f16* __restrict__ out) {
    constexpr int S = 8192;
    __shared__ f16 Ks[2][64 * 96];   // 24576 B (double-buffered, swizzled)
    __shared__ f16 Ps[256 * 72];     // 36864 B (wave-private 64-q slabs)
    const int t = threadIdx.x, lane = t & 63, w = t >> 6;
    const int c16 = lane & 15, quad = lane >> 4;
    const int id = blockIdx.x;
    const int pair = id & 127;
    const int qt = id >> 7;          // 0..3: which 256-row q tile
    const int h = pair & 15, z = pair >> 4;
    const int s0 = cu[z];

    half8 qf[4][3];
#pragma unroll
    for (int qt2 = 0; qt2 < 4; qt2++)
#pragma unroll
        for (int ks = 0; ks < 3; ks++)
            qf[qt2][ks] = *(const half8*)(qb + ((size_t)h * S + s0 + qt * 256 + w * 64 + qt2 * 16 + c16) * 96 + ks * 32 + quad * 8);

    const f16 ov = (c16 == 0) ? (f16)1.f : (f16)0.f;
    const half8 onesf = {ov, ov, ov, ov, ov, ov, ov, ov};

    const int sR = t >> 2;
    const int sK = ((t & 3) - (sR >> 1)) & 3;

    {   // stage K tile 0
        const f16* Kg = kb + ((size_t)h * S + s0) * 96;
#pragma unroll
        for (int j = 0; j < 3; j++)
            stage16(&Ks[0][0] + (j * 256 + t) * 8, Kg + (size_t)sR * 96 + j * 32 + sK * 8);
    }
    __syncthreads();

    floatx4 o[6][4] = {};   // O^T tiles [d-tile][q-subtile]; dt=5 row 80 = l

    for (int kv = 0; kv < 16; kv++) {
        if (kv < 15) {  // stage next K tile into the other buffer
            const f16* Kg = kb + ((size_t)h * S + s0 + (kv + 1) * 64) * 96;
            f16* Kd = &Ks[(kv + 1) & 1][0];
#pragma unroll
            for (int j = 0; j < 3; j++)
                stage16(Kd + (j * 256 + t) * 8, Kg + (size_t)sR * 96 + j * 32 + sK * 8);
        }
        const f16* Kc = &Ks[kv & 1][0];
        floatx4 sc[4][4] = {};
#pragma unroll
        for (int ks = 0; ks < 3; ks++) {
            half8 kf[4];
#pragma unroll
            for (int mt = 0; mt < 4; mt++) {
                const int row = mt * 16 + c16;
                kf[mt] = *(const half8*)(Kc + (ks * 256 + 4 * row + ((quad + (row >> 1)) & 3)) * 8);
            }
#pragma unroll
            for (int qt2 = 0; qt2 < 4; qt2++)
#pragma unroll
                for (int mt = 0; mt < 4; mt++)
                    sc[mt][qt2] = __builtin_amdgcn_mfma_f32_16x16x32_f16(kf[mt], qf[qt2][ks], sc[mt][qt2], 0, 0, 0);
        }
#pragma unroll
        for (int qt2 = 0; qt2 < 4; qt2++) {
            const int q = w * 64 + qt2 * 16 + c16;
#pragma unroll
            for (int mt = 0; mt < 4; mt++) {
                half4v pv;
#pragma unroll
                for (int r = 0; r < 4; r++)
                    pv[r] = (f16)__builtin_amdgcn_exp2f(sc[mt][qt2][r]);
                *(half4v*)(Ps + q * 72 + mt * 16 + quad * 4) = pv;
            }
        }
#pragma unroll
        for (int ks = 0; ks < 2; ks++) {
            const f16* Vg = vt + (size_t)h * 80 * S + s0 + kv * 64 + ks * 32;
            half8 vf[5];
#pragma unroll
            for (int dt = 0; dt < 5; dt++)
                vf[dt] = *(const half8*)(Vg + (size_t)(dt * 16 + c16) * S + quad * 8);
#pragma unroll
            for (int qt2 = 0; qt2 < 4; qt2++) {
                const int q = w * 64 + qt2 * 16 + c16;
                half8 pf = *(const half8*)(Ps + q * 72 + ks * 32 + quad * 8);
#pragma unroll
                for (int dt = 0; dt < 5; dt++)
                    o[dt][qt2] = __builtin_amdgcn_mfma_f32_16x16x32_f16(vf[dt], pf, o[dt][qt2], 0, 0, 0);
                o[5][qt2] = __builtin_amdgcn_mfma_f32_16x16x32_f16(onesf, pf, o[5][qt2], 0, 0, 0);
            }
        }
        __syncthreads();
    }
#pragma unroll
    for (int qt2 = 0; qt2 < 4; qt2++) {
        const float l = __shfl(o[5][qt2][0], c16);
        const float inv = 1.f / l;
        const size_t srow = (size_t)s0 + qt * 256 + w * 64 + qt2 * 16 + c16;
#pragma unroll
        for (int dt = 0; dt < 5; dt++)
#pragma unroll
            for (int rp = 0; rp < 2; rp++) {
                half2v hv = {(f16)(o[dt][qt2][rp * 2] * inv), (f16)(o[dt][qt2][rp * 2 + 1] * inv)};
                *(half2v*)(out + srow * 1280 + h * 80 + dt * 16 + quad * 4 + rp * 2) = hv;
            }
    }
}

// ---------------- launch: 5 dispatches ----------------
extern "C" void kernel_launch(void* const* d_in, const int* in_sizes, int n_in,
                              void* d_out, int out_size, void* d_ws, size_t ws_size,
                              hipStream_t stream) {
    const float* hidden = (const float*)d_in[0];
    const int* cu       = (const int*)d_in[1];
    const float* cosp   = (const float*)d_in[2];
    const float* sinp   = (const float*)d_in[3];
    const float* qkv_w  = (const float*)d_in[4];
    const float* qkv_b  = (const float*)d_in[5];
    const float* proj_w = (const float*)d_in[6];
    const float* proj_b = (const float*)d_in[7];
    float* out = (float*)d_out;

    constexpr size_t S = 8192, DIM = 1280, N3 = 3840;
    f16* A16   = (f16*)d_ws;
    f16* WP16  = A16 + S * DIM;          // packed qkv_w
    f16* PP16  = WP16 + N3 * DIM;        // packed proj_w
    f16* QKV16 = PP16 + DIM * DIM;
    f16* QB    = QKV16 + S * N3;
    f16* KB    = QB + (size_t)16 * S * 96;
    f16* VT    = KB + (size_t)16 * S * 96;
    f16* AT16  = A16;  // reuse: hidden-f16 dead after QKV GEMM

    prep_kernel<<<13440, 256, 0, stream>>>(hidden, A16, qkv_w, WP16, proj_w, PP16);
    gemm_bp<256><<<32 * 15, 512, 0, stream>>>(A16, WP16, qkv_b, QKV16, nullptr, 3840, 15);
    rope_kernel<<<dim3(128, 16), 320, 0, stream>>>(QKV16, cosp, sinp, QB, KB, VT);
    attn_kernel<<<512, 256, 0, stream>>>(QB, KB, VT, cu, A16);
    gemm_nt<<<640, 256, 0, stream>>>(AT16, PP16, proj_b, nullptr, out, 1280, 10);
}